// Round 10
// baseline (156.662 us; speedup 1.0000x reference)
//
#include <hip/hip_runtime.h>
#include <hip/hip_fp16.h>

#define IN_DIM 128
#define HID 64
#define XPAD 132     // padded LDS row stride for x tile
#define EPB 4096     // edges per block in bucket build
#define MAXNB 512    // max buckets (supports N <= 65536)
#define BCAP 3072    // padded slots per bucket (exp 2048, sigma~45 -> 22 sigma)

// ================= bucketed CSR build (padded buckets, no global scan) =====
// bucket b = row >> 7 (128 rows each). pairs/col_sorted live at b*BCAP.

__global__ __launch_bounds__(512) void zero_kernel(int* __restrict__ p, int n) {
    int i = threadIdx.x;
    if (i < n) p[i] = 0;
}

// pairs packed: (row_local << 16) | col   (needs N <= 65536)
__global__ __launch_bounds__(256) void bucket_fill_kernel(
        const int* __restrict__ rows, const int* __restrict__ cols,
        int* __restrict__ gcursor, int* __restrict__ pairs, int E, int NB) {
    __shared__ int cnt[MAXNB];
    __shared__ int bas[MAXNB];
    for (int i = threadIdx.x; i < NB; i += 256) cnt[i] = 0;
    __syncthreads();
    int base = blockIdx.x * EPB;
    int m = E - base; if (m > EPB) m = EPB;
    int r[16], c[16];
    #pragma unroll
    for (int u = 0; u < 16; ++u) {
        int k = u * 256 + threadIdx.x;
        r[u] = -1;
        if (k < m) {
            r[u] = rows[base + k];
            c[u] = cols[base + k];
            atomicAdd(&cnt[r[u] >> 7], 1);
        }
    }
    __syncthreads();
    // one global atomic per (block,bucket) reserves a contiguous run
    for (int i = threadIdx.x; i < NB; i += 256) {
        int cc = cnt[i];
        bas[i] = cc ? atomicAdd(&gcursor[i], cc) : 0;
        cnt[i] = 0;  // reuse as local cursor
    }
    __syncthreads();
    #pragma unroll
    for (int u = 0; u < 16; ++u) {
        if (r[u] >= 0) {
            int bkt = r[u] >> 7;
            int pos = bas[bkt] + atomicAdd(&cnt[bkt], 1);
            pairs[bkt * BCAP + pos] = ((r[u] & 127) << 16) | c[u];
        }
    }
}

// ======= fused: per-bucket counting sort (+ per-row col sort) + linear =======
// one block per bucket (128 rows). phase 1: sort edges into col_sorted with
// cols ascending per row; emit row_range + norm (global + LDS). phase 2:
// linear xs = fp16(norm*(x@W+bias)) for the same 128 rows, 2x 64-row halves.

__global__ __launch_bounds__(256) void sort_linear_kernel(
        const int* __restrict__ pairs, const int* __restrict__ gcursor,
        const float* __restrict__ x, const float* __restrict__ W,
        const float* __restrict__ bias,
        int2* __restrict__ row_range, int* __restrict__ col_sorted,
        float* __restrict__ norm_g, uint2* __restrict__ xs, int N) {
    __shared__ float xl[64 * XPAD];      // 33.8 KB; aliased as colbuf in phase 1
    __shared__ int cnt[128];
    __shared__ int scan_s[128];
    __shared__ float nrm[128];
    int* colbuf = (int*)xl;              // needs BCAP*4 = 12 KB <= 33.8 KB

    const int t = threadIdx.x;
    const int bkt = blockIdx.x;
    const int r0 = bkt << 7;
    const int pb = bkt * BCAP;
    const int m = gcursor[bkt];          // bucket edge count

    // ---- phase 1: counting sort by row into LDS ----
    if (t < 128) cnt[t] = 0;
    __syncthreads();
    for (int k = t; k < m; k += 256)
        atomicAdd(&cnt[pairs[pb + k] >> 16], 1);
    __syncthreads();

    int v = (t < 128) ? cnt[t] : 0;
    if (t < 128) scan_s[t] = v;
    __syncthreads();
    #pragma unroll
    for (int off = 1; off < 128; off <<= 1) {
        int tmp = (t < 128 && t >= off) ? scan_s[t - off] : 0;
        __syncthreads();
        if (t < 128) scan_s[t] += tmp;
        __syncthreads();
    }
    int ex = 0;
    if (t < 128) {
        ex = scan_s[t] - v;              // exclusive start within bucket
        int rr = r0 + t;
        float nv = rsqrtf(1.0f + (float)v);
        nrm[t] = nv;
        if (rr < N) {
            row_range[rr] = make_int2(pb + ex, pb + ex + v);
            norm_g[rr]    = nv;
        }
        cnt[t] = ex;                     // reuse as per-row cursor
    }
    __syncthreads();
    for (int k = t; k < m; k += 256) {
        int p = pairs[pb + k];
        int pos = atomicAdd(&cnt[p >> 16], 1);
        colbuf[pos] = p & 0xFFFF;
    }
    __syncthreads();
    // per-row insertion sort (ascending cols) for gather locality
    if (t < 128) {
        for (int i = ex + 1; i < ex + v; ++i) {
            int key = colbuf[i];
            int j = i - 1;
            while (j >= ex && colbuf[j] > key) { colbuf[j + 1] = colbuf[j]; --j; }
            colbuf[j + 1] = key;
        }
    }
    __syncthreads();
    for (int k = t; k < m; k += 256)
        col_sorted[pb + k] = colbuf[k];

    // ---- phase 2: linear for rows r0..r0+127, two 64-row halves ----
    const int c4 = t & 15;               // features c4*4 .. c4*4+3
    const int rg = t >> 4;               // row group (4 rows)
    const float4 bv = reinterpret_cast<const float4*>(bias)[c4];
    const float4* Wv = reinterpret_cast<const float4*>(W);

    for (int half = 0; half < 2; ++half) {
        const int hrow0 = r0 + half * 64;
        __syncthreads();                 // previous xl/colbuf use complete
        for (int idx = t; idx < 64 * 32; idx += 256) {
            int r = idx >> 5, cc = idx & 31;
            int gr = hrow0 + r;
            float4 vv = make_float4(0.f, 0.f, 0.f, 0.f);
            if (gr < N) vv = reinterpret_cast<const float4*>(x)[(size_t)gr * 32 + cc];
            *reinterpret_cast<float4*>(&xl[r * XPAD + cc * 4]) = vv;
        }
        __syncthreads();

        float4 acc[4];
        #pragma unroll
        for (int rr = 0; rr < 4; ++rr) acc[rr] = bv;
        for (int k0 = 0; k0 < IN_DIM; k0 += 4) {
            float4 w0 = Wv[(k0 + 0) * 16 + c4];
            float4 w1 = Wv[(k0 + 1) * 16 + c4];
            float4 w2 = Wv[(k0 + 2) * 16 + c4];
            float4 w3 = Wv[(k0 + 3) * 16 + c4];
            #pragma unroll
            for (int rr = 0; rr < 4; ++rr) {
                float4 xv = *reinterpret_cast<const float4*>(&xl[(rg * 4 + rr) * XPAD + k0]);
                acc[rr].x = fmaf(xv.x, w0.x, acc[rr].x);
                acc[rr].y = fmaf(xv.x, w0.y, acc[rr].y);
                acc[rr].z = fmaf(xv.x, w0.z, acc[rr].z);
                acc[rr].w = fmaf(xv.x, w0.w, acc[rr].w);
                acc[rr].x = fmaf(xv.y, w1.x, acc[rr].x);
                acc[rr].y = fmaf(xv.y, w1.y, acc[rr].y);
                acc[rr].z = fmaf(xv.y, w1.z, acc[rr].z);
                acc[rr].w = fmaf(xv.y, w1.w, acc[rr].w);
                acc[rr].x = fmaf(xv.z, w2.x, acc[rr].x);
                acc[rr].y = fmaf(xv.z, w2.y, acc[rr].y);
                acc[rr].z = fmaf(xv.z, w2.z, acc[rr].z);
                acc[rr].w = fmaf(xv.z, w2.w, acc[rr].w);
                acc[rr].x = fmaf(xv.w, w3.x, acc[rr].x);
                acc[rr].y = fmaf(xv.w, w3.y, acc[rr].y);
                acc[rr].z = fmaf(xv.w, w3.z, acc[rr].z);
                acc[rr].w = fmaf(xv.w, w3.w, acc[rr].w);
            }
        }

        #pragma unroll
        for (int rr = 0; rr < 4; ++rr) {
            int lr = rg * 4 + rr;        // local row 0..63
            int gr = hrow0 + lr;
            if (gr >= N) continue;
            float nv = nrm[half * 64 + lr];
            __half2 h0 = __floats2half2_rn(nv * acc[rr].x, nv * acc[rr].y);
            __half2 h1 = __floats2half2_rn(nv * acc[rr].z, nv * acc[rr].w);
            uint2 pk;
            pk.x = *reinterpret_cast<unsigned int*>(&h0);
            pk.y = *reinterpret_cast<unsigned int*>(&h1);
            xs[(size_t)gr * 16 + c4] = pk;
        }
    }
}

// ================= fused GCN layer (fp16 xs, fp32 accumulate) =================
// wave per node; lane = (g = lane>>4 edge-slot 0..3, f = lane&15 uint2 idx).

__global__ __launch_bounds__(256) void layer_kernel(
        const int2* __restrict__ row_range, const int* __restrict__ col_sorted,
        const uint2* __restrict__ xin, const float* __restrict__ norm,
        void* __restrict__ xout_v, int N, int last) {
    int node = (blockIdx.x * blockDim.x + threadIdx.x) >> 6;
    int lane = threadIdx.x & 63;
    if (node >= N) return;
    const int f = lane & 15;      // features 4f .. 4f+3
    const int g = lane >> 4;      // edge slot 0..3

    int2 rr = row_range[node];
    int be = rr.x;
    int en = rr.y;
    float ax = 0.f, ay = 0.f, az = 0.f, aw = 0.f;

    for (int base = be; base < en; base += 64) {
        int m = en - base;
        if (m > 64) m = 64;
        int cv = (lane < m) ? col_sorted[base + lane] : 0;
        int t = 0;
        for (; t + 16 <= m; t += 16) {   // 16 edges: 4 loads, 4 shfl
            int c0 = __shfl(cv, t + 0 + g, 64);
            int c1 = __shfl(cv, t + 4 + g, 64);
            int c2 = __shfl(cv, t + 8 + g, 64);
            int c3 = __shfl(cv, t + 12 + g, 64);
            uint2 u0 = xin[(size_t)c0 * 16 + f];
            uint2 u1 = xin[(size_t)c1 * 16 + f];
            uint2 u2 = xin[(size_t)c2 * 16 + f];
            uint2 u3 = xin[(size_t)c3 * 16 + f];
            float2 p0 = __half22float2(*reinterpret_cast<__half2*>(&u0.x));
            float2 q0 = __half22float2(*reinterpret_cast<__half2*>(&u0.y));
            float2 p1 = __half22float2(*reinterpret_cast<__half2*>(&u1.x));
            float2 q1 = __half22float2(*reinterpret_cast<__half2*>(&u1.y));
            float2 p2 = __half22float2(*reinterpret_cast<__half2*>(&u2.x));
            float2 q2 = __half22float2(*reinterpret_cast<__half2*>(&u2.y));
            float2 p3 = __half22float2(*reinterpret_cast<__half2*>(&u3.x));
            float2 q3 = __half22float2(*reinterpret_cast<__half2*>(&u3.y));
            ax += (p0.x + p1.x) + (p2.x + p3.x);
            ay += (p0.y + p1.y) + (p2.y + p3.y);
            az += (q0.x + q1.x) + (q2.x + q3.x);
            aw += (q0.y + q1.y) + (q2.y + q3.y);
        }
        for (; t + 4 <= m; t += 4) {     // 4 edges: 1 load, 1 shfl
            int c = __shfl(cv, t + g, 64);
            uint2 u = xin[(size_t)c * 16 + f];
            float2 p = __half22float2(*reinterpret_cast<__half2*>(&u.x));
            float2 q = __half22float2(*reinterpret_cast<__half2*>(&u.y));
            ax += p.x; ay += p.y; az += q.x; aw += q.y;
        }
        int rem = m - t;
        if (rem > 0) {                   // tail: slots g < rem participate
            int c = __shfl(cv, t + g, 64);
            if (g < rem) {
                uint2 u = xin[(size_t)c * 16 + f];
                float2 p = __half22float2(*reinterpret_cast<__half2*>(&u.x));
                float2 q = __half22float2(*reinterpret_cast<__half2*>(&u.y));
                ax += p.x; ay += p.y; az += q.x; aw += q.y;
            }
        }
    }

    // reduce edge slots (lane bits 4,5)
    ax += __shfl_xor(ax, 16, 64); ax += __shfl_xor(ax, 32, 64);
    ay += __shfl_xor(ay, 16, 64); ay += __shfl_xor(ay, 32, 64);
    az += __shfl_xor(az, 16, 64); az += __shfl_xor(az, 32, 64);
    aw += __shfl_xor(aw, 16, 64); aw += __shfl_xor(aw, 32, 64);

    uint2 us = xin[(size_t)node * 16 + f];
    float2 sp = __half22float2(*reinterpret_cast<__half2*>(&us.x));
    float2 sq = __half22float2(*reinterpret_cast<__half2*>(&us.y));
    float nv = norm[node];
    float hx = nv * (ax + sp.x);
    float hy = nv * (ay + sp.y);
    float hz = nv * (az + sq.x);
    float hw = nv * (aw + sq.y);
    if (g == 0) {
        if (last) {
            reinterpret_cast<float4*>(xout_v)[(size_t)node * 16 + f] =
                make_float4(hx, hy, hz, hw);
        } else {
            __half2 o0 = __floats2half2_rn(nv * hx, nv * hy);
            __half2 o1 = __floats2half2_rn(nv * hz, nv * hw);
            uint2 pk;
            pk.x = *reinterpret_cast<unsigned int*>(&o0);
            pk.y = *reinterpret_cast<unsigned int*>(&o1);
            reinterpret_cast<uint2*>(xout_v)[(size_t)node * 16 + f] = pk;
        }
    }
}

extern "C" void kernel_launch(void* const* d_in, const int* in_sizes, int n_in,
                              void* d_out, int out_size, void* d_ws, size_t ws_size,
                              hipStream_t stream) {
    const float* x  = (const float*)d_in[0];
    const int*   ei = (const int*)d_in[1];
    const float* W  = (const float*)d_in[2];
    const float* b  = (const float*)d_in[3];
    float* out = (float*)d_out;

    const int N = in_sizes[0] / IN_DIM;
    const int E = in_sizes[1] / 2;
    const int* rows = ei;
    const int* cols = ei + E;
    const int NB = (N + 127) >> 7;

    char* wp = (char*)d_ws;
    auto alloc = [&](size_t bytes) {
        char* r = wp;
        wp += (bytes + 15) & ~(size_t)15;
        return r;
    };
    int*   pairs      = (int*)alloc((size_t)NB * BCAP * sizeof(int));
    int*   col_sorted = (int*)alloc((size_t)NB * BCAP * sizeof(int));
    int*   gcursor    = (int*)alloc(MAXNB * sizeof(int));
    int2*  row_range  = (int2*)alloc((size_t)N * sizeof(int2));
    float* norm       = (float*)alloc((size_t)N * sizeof(float));
    uint2* xsA        = (uint2*)alloc((size_t)N * 16 * sizeof(uint2));
    uint2* xsB        = (uint2*)alloc((size_t)N * 16 * sizeof(uint2));

    const int eblocks = (E + EPB - 1) / EPB;

    // ---- build + linear: zero -> fill -> fused sort+linear ----
    zero_kernel<<<1, 512, 0, stream>>>(gcursor, MAXNB);
    bucket_fill_kernel<<<eblocks, 256, 0, stream>>>(rows, cols, gcursor, pairs, E, NB);
    sort_linear_kernel<<<NB, 256, 0, stream>>>(pairs, gcursor, x, W, b,
                                               row_range, col_sorted, norm, xsA, N);

    // ---- 3 layers: xsA -> xsB -> xsA -> out(f32) ----
    const int blocks = (N * 64 + 255) / 256;
    layer_kernel<<<blocks, 256, 0, stream>>>(row_range, col_sorted, xsA, norm, xsB, N, 0);
    layer_kernel<<<blocks, 256, 0, stream>>>(row_range, col_sorted, xsB, norm, xsA, N, 0);
    layer_kernel<<<blocks, 256, 0, stream>>>(row_range, col_sorted, xsA, norm, out, N, 1);
}

// Round 11
// 131.883 us; speedup vs baseline: 1.1879x; 1.1879x over previous
//
#include <hip/hip_runtime.h>
#include <hip/hip_fp16.h>

#define IN_DIM 128
#define HID 64
#define XPAD 132     // padded LDS row stride for x tile
#define EPB 4096     // edges per block in bucket build
#define MAXNB 512    // max buckets (supports N <= 65536)
#define BCAP 3072    // padded slots per bucket (exp 2048, sigma~45 -> 22 sigma)

typedef int   i32x4 __attribute__((ext_vector_type(4)));
typedef unsigned int u32x2 __attribute__((ext_vector_type(2)));
typedef float f32x4 __attribute__((ext_vector_type(4)));

// ================= bucketed CSR build (padded buckets, no global scan) =====
// bucket b = row >> 7 (128 rows each). pairs/col_sorted live at b*BCAP.

__global__ __launch_bounds__(512) void zero_kernel(int* __restrict__ p, int n) {
    int i = threadIdx.x;
    if (i < n) p[i] = 0;
}

// pairs packed: (row_local << 16) | col   (needs N <= 65536)
__global__ __launch_bounds__(256) void bucket_fill_kernel(
        const int* __restrict__ rows, const int* __restrict__ cols,
        int* __restrict__ gcursor, int* __restrict__ pairs, int E, int NB) {
    __shared__ int cnt[MAXNB];
    __shared__ int bas[MAXNB];
    for (int i = threadIdx.x; i < NB; i += 256) cnt[i] = 0;
    __syncthreads();
    int base = blockIdx.x * EPB;
    int m = E - base; if (m > EPB) m = EPB;
    int mv4 = m & ~3;

    i32x4 rv[4], cv[4];
    bool ok[4];
    #pragma unroll
    for (int u = 0; u < 4; ++u) {
        int k4 = u * 1024 + threadIdx.x * 4;
        ok[u] = (k4 < mv4);
        if (ok[u]) {
            rv[u] = __builtin_nontemporal_load(
                        reinterpret_cast<const i32x4*>(rows + base + k4));
            cv[u] = __builtin_nontemporal_load(
                        reinterpret_cast<const i32x4*>(cols + base + k4));
            #pragma unroll
            for (int j = 0; j < 4; ++j) atomicAdd(&cnt[rv[u][j] >> 7], 1);
        }
    }
    int rt = -1, ct = 0;
    {
        int kt = mv4 + threadIdx.x;
        if (kt < m) {
            rt = rows[base + kt];
            ct = cols[base + kt];
            atomicAdd(&cnt[rt >> 7], 1);
        }
    }
    __syncthreads();
    // one global atomic per (block,bucket) reserves a contiguous run
    for (int i = threadIdx.x; i < NB; i += 256) {
        int cc = cnt[i];
        bas[i] = cc ? atomicAdd(&gcursor[i], cc) : 0;
        cnt[i] = 0;  // reuse as local cursor
    }
    __syncthreads();
    #pragma unroll
    for (int u = 0; u < 4; ++u) {
        if (ok[u]) {
            #pragma unroll
            for (int j = 0; j < 4; ++j) {
                int r = rv[u][j];
                int bkt = r >> 7;
                int pos = bas[bkt] + atomicAdd(&cnt[bkt], 1);
                pairs[bkt * BCAP + pos] = ((r & 127) << 16) | cv[u][j];
            }
        }
    }
    if (rt >= 0) {
        int bkt = rt >> 7;
        int pos = bas[bkt] + atomicAdd(&cnt[bkt], 1);
        pairs[bkt * BCAP + pos] = ((rt & 127) << 16) | ct;
    }
}

// one block per bucket: local counting sort -> row_range(int2), norm, col_sorted
__global__ __launch_bounds__(256) void bucket_sort_kernel(
        const int* __restrict__ pairs, const int* __restrict__ gcursor,
        int2* __restrict__ row_range, int* __restrict__ col_sorted,
        float* __restrict__ norm, int N) {
    __shared__ int cnt[128];
    __shared__ int scan[128];
    const int t = threadIdx.x;
    const int r0 = blockIdx.x << 7;
    const int pb = blockIdx.x * BCAP;
    const int m = gcursor[blockIdx.x];   // bucket count (cursor == count after fill)

    if (t < 128) cnt[t] = 0;
    __syncthreads();
    for (int k = t; k < m; k += 256)
        atomicAdd(&cnt[__builtin_nontemporal_load(&pairs[pb + k]) >> 16], 1);
    __syncthreads();

    int v = (t < 128) ? cnt[t] : 0;
    if (t < 128) scan[t] = v;
    __syncthreads();
    #pragma unroll
    for (int off = 1; off < 128; off <<= 1) {
        int tmp = (t < 128 && t >= off) ? scan[t - off] : 0;
        __syncthreads();
        if (t < 128) scan[t] += tmp;
        __syncthreads();
    }
    if (t < 128) {
        int ex = scan[t] - v;            // exclusive within bucket
        int rr = r0 + t;
        if (rr < N) {
            row_range[rr] = make_int2(pb + ex, pb + ex + v);
            norm[rr]      = rsqrtf(1.0f + (float)v);
        }
        cnt[t] = ex;                     // reuse as per-row cursor
    }
    __syncthreads();
    for (int k = t; k < m; k += 256) {
        int p = __builtin_nontemporal_load(&pairs[pb + k]);
        int pos = pb + atomicAdd(&cnt[p >> 16], 1);
        col_sorted[pos] = p & 0xFFFF;    // scattered 4B: keep cached (L2 merge)
    }
}

// ================= fused linear (x@W + b) * norm -> fp16 =================
// output: xs[node][16] uint2 (each uint2 = 4 features as 2x half2)

__global__ __launch_bounds__(256) void linear_kernel(
        const float* __restrict__ x, const float* __restrict__ W,
        const float* __restrict__ b, const float* __restrict__ norm,
        uint2* __restrict__ xs, int N) {
    __shared__ float xl[64 * XPAD];
    const int tid = threadIdx.x;
    const int row0 = blockIdx.x * 64;

    const f32x4* xv4 = reinterpret_cast<const f32x4*>(x);
    for (int idx = tid; idx < 64 * (IN_DIM / 4); idx += 256) {
        int r = idx >> 5;
        int c4 = idx & 31;
        int gr = row0 + r;
        f32x4 v = {0.f, 0.f, 0.f, 0.f};
        if (gr < N) v = __builtin_nontemporal_load(&xv4[(size_t)gr * 32 + c4]);
        *reinterpret_cast<f32x4*>(&xl[r * XPAD + c4 * 4]) = v;
    }
    __syncthreads();

    const int c4 = tid & 15;      // features c4*4 .. c4*4+3
    const int rg = tid >> 4;
    const float4 bv = reinterpret_cast<const float4*>(b)[c4];
    float4 acc[4];
    #pragma unroll
    for (int rr = 0; rr < 4; ++rr) acc[rr] = bv;

    const float4* Wv = reinterpret_cast<const float4*>(W);  // cached: heavy reuse
    for (int k0 = 0; k0 < IN_DIM; k0 += 4) {
        float4 w0 = Wv[(k0 + 0) * 16 + c4];
        float4 w1 = Wv[(k0 + 1) * 16 + c4];
        float4 w2 = Wv[(k0 + 2) * 16 + c4];
        float4 w3 = Wv[(k0 + 3) * 16 + c4];
        #pragma unroll
        for (int rr = 0; rr < 4; ++rr) {
            float4 xv = *reinterpret_cast<const float4*>(&xl[(rg * 4 + rr) * XPAD + k0]);
            acc[rr].x = fmaf(xv.x, w0.x, acc[rr].x);
            acc[rr].y = fmaf(xv.x, w0.y, acc[rr].y);
            acc[rr].z = fmaf(xv.x, w0.z, acc[rr].z);
            acc[rr].w = fmaf(xv.x, w0.w, acc[rr].w);
            acc[rr].x = fmaf(xv.y, w1.x, acc[rr].x);
            acc[rr].y = fmaf(xv.y, w1.y, acc[rr].y);
            acc[rr].z = fmaf(xv.y, w1.z, acc[rr].z);
            acc[rr].w = fmaf(xv.y, w1.w, acc[rr].w);
            acc[rr].x = fmaf(xv.z, w2.x, acc[rr].x);
            acc[rr].y = fmaf(xv.z, w2.y, acc[rr].y);
            acc[rr].z = fmaf(xv.z, w2.z, acc[rr].z);
            acc[rr].w = fmaf(xv.z, w2.w, acc[rr].w);
            acc[rr].x = fmaf(xv.w, w3.x, acc[rr].x);
            acc[rr].y = fmaf(xv.w, w3.y, acc[rr].y);
            acc[rr].z = fmaf(xv.w, w3.z, acc[rr].z);
            acc[rr].w = fmaf(xv.w, w3.w, acc[rr].w);
        }
    }

    #pragma unroll
    for (int rr = 0; rr < 4; ++rr) {
        int gr = row0 + rg * 4 + rr;
        if (gr >= N) continue;
        float nv = norm[gr];
        __half2 h0 = __floats2half2_rn(nv * acc[rr].x, nv * acc[rr].y);
        __half2 h1 = __floats2half2_rn(nv * acc[rr].z, nv * acc[rr].w);
        u32x2 pk = {*reinterpret_cast<unsigned int*>(&h0),
                    *reinterpret_cast<unsigned int*>(&h1)};
        __builtin_nontemporal_store(pk,
            reinterpret_cast<u32x2*>(&xs[(size_t)gr * 16 + c4]));
    }
}

// ================= fused GCN layer (fp16 xs, fp32 accumulate) =================
// wave per node; lane = (g = lane>>4 edge-slot 0..3, f = lane&15 uint2 idx).

__global__ __launch_bounds__(256) void layer_kernel(
        const int2* __restrict__ row_range, const int* __restrict__ col_sorted,
        const uint2* __restrict__ xin, const float* __restrict__ norm,
        void* __restrict__ xout_v, int N, int last) {
    int node = (blockIdx.x * blockDim.x + threadIdx.x) >> 6;
    int lane = threadIdx.x & 63;
    if (node >= N) return;
    const int f = lane & 15;      // features 4f .. 4f+3
    const int g = lane >> 4;      // edge slot 0..3

    int2 rr = row_range[node];
    int be = rr.x;
    int en = rr.y;
    float ax = 0.f, ay = 0.f, az = 0.f, aw = 0.f;

    for (int base = be; base < en; base += 64) {
        int m = en - base;
        if (m > 64) m = 64;
        int cv = (lane < m) ? __builtin_nontemporal_load(&col_sorted[base + lane]) : 0;
        int t = 0;
        for (; t + 16 <= m; t += 16) {   // 16 edges: 4 loads, 4 shfl
            int c0 = __shfl(cv, t + 0 + g, 64);
            int c1 = __shfl(cv, t + 4 + g, 64);
            int c2 = __shfl(cv, t + 8 + g, 64);
            int c3 = __shfl(cv, t + 12 + g, 64);
            uint2 u0 = xin[(size_t)c0 * 16 + f];
            uint2 u1 = xin[(size_t)c1 * 16 + f];
            uint2 u2 = xin[(size_t)c2 * 16 + f];
            uint2 u3 = xin[(size_t)c3 * 16 + f];
            float2 p0 = __half22float2(*reinterpret_cast<__half2*>(&u0.x));
            float2 q0 = __half22float2(*reinterpret_cast<__half2*>(&u0.y));
            float2 p1 = __half22float2(*reinterpret_cast<__half2*>(&u1.x));
            float2 q1 = __half22float2(*reinterpret_cast<__half2*>(&u1.y));
            float2 p2 = __half22float2(*reinterpret_cast<__half2*>(&u2.x));
            float2 q2 = __half22float2(*reinterpret_cast<__half2*>(&u2.y));
            float2 p3 = __half22float2(*reinterpret_cast<__half2*>(&u3.x));
            float2 q3 = __half22float2(*reinterpret_cast<__half2*>(&u3.y));
            ax += (p0.x + p1.x) + (p2.x + p3.x);
            ay += (p0.y + p1.y) + (p2.y + p3.y);
            az += (q0.x + q1.x) + (q2.x + q3.x);
            aw += (q0.y + q1.y) + (q2.y + q3.y);
        }
        for (; t + 4 <= m; t += 4) {     // 4 edges: 1 load, 1 shfl
            int c = __shfl(cv, t + g, 64);
            uint2 u = xin[(size_t)c * 16 + f];
            float2 p = __half22float2(*reinterpret_cast<__half2*>(&u.x));
            float2 q = __half22float2(*reinterpret_cast<__half2*>(&u.y));
            ax += p.x; ay += p.y; az += q.x; aw += q.y;
        }
        int rem = m - t;
        if (rem > 0) {                   // tail: slots g < rem participate
            int c = __shfl(cv, t + g, 64);
            if (g < rem) {
                uint2 u = xin[(size_t)c * 16 + f];
                float2 p = __half22float2(*reinterpret_cast<__half2*>(&u.x));
                float2 q = __half22float2(*reinterpret_cast<__half2*>(&u.y));
                ax += p.x; ay += p.y; az += q.x; aw += q.y;
            }
        }
    }

    // reduce edge slots (lane bits 4,5)
    ax += __shfl_xor(ax, 16, 64); ax += __shfl_xor(ax, 32, 64);
    ay += __shfl_xor(ay, 16, 64); ay += __shfl_xor(ay, 32, 64);
    az += __shfl_xor(az, 16, 64); az += __shfl_xor(az, 32, 64);
    aw += __shfl_xor(aw, 16, 64); aw += __shfl_xor(aw, 32, 64);

    uint2 us = xin[(size_t)node * 16 + f];
    float2 sp = __half22float2(*reinterpret_cast<__half2*>(&us.x));
    float2 sq = __half22float2(*reinterpret_cast<__half2*>(&us.y));
    float nv = norm[node];
    float hx = nv * (ax + sp.x);
    float hy = nv * (ay + sp.y);
    float hz = nv * (az + sq.x);
    float hw = nv * (aw + sq.y);
    if (g == 0) {
        if (last) {
            f32x4 o = {hx, hy, hz, hw};
            __builtin_nontemporal_store(o,
                reinterpret_cast<f32x4*>((float*)xout_v + (size_t)node * 64 + f * 4));
        } else {
            __half2 o0 = __floats2half2_rn(nv * hx, nv * hy);
            __half2 o1 = __floats2half2_rn(nv * hz, nv * hw);
            u32x2 pk = {*reinterpret_cast<unsigned int*>(&o0),
                        *reinterpret_cast<unsigned int*>(&o1)};
            __builtin_nontemporal_store(pk,
                reinterpret_cast<u32x2*>((uint2*)xout_v + (size_t)node * 16 + f));
        }
    }
}

extern "C" void kernel_launch(void* const* d_in, const int* in_sizes, int n_in,
                              void* d_out, int out_size, void* d_ws, size_t ws_size,
                              hipStream_t stream) {
    const float* x  = (const float*)d_in[0];
    const int*   ei = (const int*)d_in[1];
    const float* W  = (const float*)d_in[2];
    const float* b  = (const float*)d_in[3];
    float* out = (float*)d_out;

    const int N = in_sizes[0] / IN_DIM;
    const int E = in_sizes[1] / 2;
    const int* rows = ei;
    const int* cols = ei + E;
    const int NB = (N + 127) >> 7;

    char* wp = (char*)d_ws;
    auto alloc = [&](size_t bytes) {
        char* r = wp;
        wp += (bytes + 15) & ~(size_t)15;
        return r;
    };
    int*   pairs      = (int*)alloc((size_t)NB * BCAP * sizeof(int));
    int*   col_sorted = (int*)alloc((size_t)NB * BCAP * sizeof(int));
    int*   gcursor    = (int*)alloc(MAXNB * sizeof(int));
    int2*  row_range  = (int2*)alloc((size_t)N * sizeof(int2));
    float* norm       = (float*)alloc((size_t)N * sizeof(float));
    uint2* xsA        = (uint2*)alloc((size_t)N * 16 * sizeof(uint2));
    uint2* xsB        = (uint2*)alloc((size_t)N * 16 * sizeof(uint2));

    const int eblocks = (E + EPB - 1) / EPB;

    // ---- bucketed CSR build: zero -> fill -> sort ----
    zero_kernel<<<1, 512, 0, stream>>>(gcursor, MAXNB);
    bucket_fill_kernel<<<eblocks, 256, 0, stream>>>(rows, cols, gcursor, pairs, E, NB);
    bucket_sort_kernel<<<NB, 256, 0, stream>>>(pairs, gcursor, row_range, col_sorted, norm, N);

    // ---- xsA = fp16( norm * (x @ W + b) ) ----
    linear_kernel<<<(N + 63) / 64, 256, 0, stream>>>(x, W, b, norm, xsA, N);

    // ---- 3 layers: xsA -> xsB -> xsA -> out(f32) ----
    const int blocks = (N * 64 + 255) / 256;
    layer_kernel<<<blocks, 256, 0, stream>>>(row_range, col_sorted, xsA, norm, xsB, N, 0);
    layer_kernel<<<blocks, 256, 0, stream>>>(row_range, col_sorted, xsB, norm, xsA, N, 0);
    layer_kernel<<<blocks, 256, 0, stream>>>(row_range, col_sorted, xsA, norm, out, N, 1);
}

// Round 12
// 127.231 us; speedup vs baseline: 1.2313x; 1.0366x over previous
//
#include <hip/hip_runtime.h>
#include <hip/hip_fp16.h>

#define IN_DIM 128
#define HID 64
#define XPAD 132     // padded LDS row stride for x tile
#define EPB 4096     // edges per block in bucket build
#define MAXNB 512    // max buckets (supports N <= 65536)
#define BCAP 3072    // padded slots per bucket (exp 2048, sigma~45 -> 22 sigma)

// ================= bucketed CSR build (padded buckets, no global scan) =====
// bucket b = row >> 7 (128 rows each). pairs/col_sorted live at b*BCAP.

__global__ __launch_bounds__(512) void zero_kernel(int* __restrict__ p, int n) {
    int i = threadIdx.x;
    if (i < n) p[i] = 0;
}

// pairs packed: (row_local << 16) | col   (needs N <= 65536)
__global__ __launch_bounds__(256) void bucket_fill_kernel(
        const int* __restrict__ rows, const int* __restrict__ cols,
        int* __restrict__ gcursor, int* __restrict__ pairs, int E, int NB) {
    __shared__ int cnt[MAXNB];
    __shared__ int bas[MAXNB];
    for (int i = threadIdx.x; i < NB; i += 256) cnt[i] = 0;
    __syncthreads();
    int base = blockIdx.x * EPB;
    int m = E - base; if (m > EPB) m = EPB;
    int r[16], c[16];
    #pragma unroll
    for (int u = 0; u < 16; ++u) {
        int k = u * 256 + threadIdx.x;
        r[u] = -1;
        if (k < m) {
            r[u] = rows[base + k];
            c[u] = cols[base + k];
            atomicAdd(&cnt[r[u] >> 7], 1);
        }
    }
    __syncthreads();
    // one global atomic per (block,bucket) reserves a contiguous run
    for (int i = threadIdx.x; i < NB; i += 256) {
        int cc = cnt[i];
        bas[i] = cc ? atomicAdd(&gcursor[i], cc) : 0;
        cnt[i] = 0;  // reuse as local cursor
    }
    __syncthreads();
    #pragma unroll
    for (int u = 0; u < 16; ++u) {
        if (r[u] >= 0) {
            int bkt = r[u] >> 7;
            int pos = bas[bkt] + atomicAdd(&cnt[bkt], 1);
            pairs[bkt * BCAP + pos] = ((r[u] & 127) << 16) | c[u];
        }
    }
}

// one block per bucket: local counting sort -> row_range(int2), norm, col_sorted
__global__ __launch_bounds__(256) void bucket_sort_kernel(
        const int* __restrict__ pairs, const int* __restrict__ gcursor,
        int2* __restrict__ row_range, int* __restrict__ col_sorted,
        float* __restrict__ norm, int N) {
    __shared__ int cnt[128];
    __shared__ int scan[128];
    const int t = threadIdx.x;
    const int r0 = blockIdx.x << 7;
    const int pb = blockIdx.x * BCAP;
    const int m = gcursor[blockIdx.x];   // bucket count (cursor == count after fill)

    if (t < 128) cnt[t] = 0;
    __syncthreads();
    for (int k = t; k < m; k += 256)
        atomicAdd(&cnt[pairs[pb + k] >> 16], 1);
    __syncthreads();

    int v = (t < 128) ? cnt[t] : 0;
    if (t < 128) scan[t] = v;
    __syncthreads();
    #pragma unroll
    for (int off = 1; off < 128; off <<= 1) {
        int tmp = (t < 128 && t >= off) ? scan[t - off] : 0;
        __syncthreads();
        if (t < 128) scan[t] += tmp;
        __syncthreads();
    }
    if (t < 128) {
        int ex = scan[t] - v;            // exclusive within bucket
        int rr = r0 + t;
        if (rr < N) {
            row_range[rr] = make_int2(pb + ex, pb + ex + v);
            norm[rr]      = rsqrtf(1.0f + (float)v);
        }
        cnt[t] = ex;                     // reuse as per-row cursor
    }
    __syncthreads();
    for (int k = t; k < m; k += 256) {
        int p = pairs[pb + k];
        int pos = pb + atomicAdd(&cnt[p >> 16], 1);
        col_sorted[pos] = p & 0xFFFF;
    }
}

// ================= fused linear (x@W + b) * norm -> fp16 =================
// output: xs[node][16] uint2 (each uint2 = 4 features as 2x half2)

__global__ __launch_bounds__(256) void linear_kernel(
        const float* __restrict__ x, const float* __restrict__ W,
        const float* __restrict__ b, const float* __restrict__ norm,
        uint2* __restrict__ xs, int N) {
    __shared__ float xl[64 * XPAD];
    const int tid = threadIdx.x;
    const int row0 = blockIdx.x * 64;

    for (int idx = tid; idx < 64 * (IN_DIM / 4); idx += 256) {
        int r = idx >> 5;
        int c4 = idx & 31;
        int gr = row0 + r;
        float4 v = make_float4(0.f, 0.f, 0.f, 0.f);
        if (gr < N) v = reinterpret_cast<const float4*>(x)[(size_t)gr * 32 + c4];
        *reinterpret_cast<float4*>(&xl[r * XPAD + c4 * 4]) = v;
    }
    __syncthreads();

    const int c4 = tid & 15;      // features c4*4 .. c4*4+3
    const int rg = tid >> 4;
    const float4 bv = reinterpret_cast<const float4*>(b)[c4];
    float4 acc[4];
    #pragma unroll
    for (int rr = 0; rr < 4; ++rr) acc[rr] = bv;

    const float4* Wv = reinterpret_cast<const float4*>(W);
    for (int k0 = 0; k0 < IN_DIM; k0 += 4) {
        float4 w0 = Wv[(k0 + 0) * 16 + c4];
        float4 w1 = Wv[(k0 + 1) * 16 + c4];
        float4 w2 = Wv[(k0 + 2) * 16 + c4];
        float4 w3 = Wv[(k0 + 3) * 16 + c4];
        #pragma unroll
        for (int rr = 0; rr < 4; ++rr) {
            float4 xv = *reinterpret_cast<const float4*>(&xl[(rg * 4 + rr) * XPAD + k0]);
            acc[rr].x = fmaf(xv.x, w0.x, acc[rr].x);
            acc[rr].y = fmaf(xv.x, w0.y, acc[rr].y);
            acc[rr].z = fmaf(xv.x, w0.z, acc[rr].z);
            acc[rr].w = fmaf(xv.x, w0.w, acc[rr].w);
            acc[rr].x = fmaf(xv.y, w1.x, acc[rr].x);
            acc[rr].y = fmaf(xv.y, w1.y, acc[rr].y);
            acc[rr].z = fmaf(xv.y, w1.z, acc[rr].z);
            acc[rr].w = fmaf(xv.y, w1.w, acc[rr].w);
            acc[rr].x = fmaf(xv.z, w2.x, acc[rr].x);
            acc[rr].y = fmaf(xv.z, w2.y, acc[rr].y);
            acc[rr].z = fmaf(xv.z, w2.z, acc[rr].z);
            acc[rr].w = fmaf(xv.z, w2.w, acc[rr].w);
            acc[rr].x = fmaf(xv.w, w3.x, acc[rr].x);
            acc[rr].y = fmaf(xv.w, w3.y, acc[rr].y);
            acc[rr].z = fmaf(xv.w, w3.z, acc[rr].z);
            acc[rr].w = fmaf(xv.w, w3.w, acc[rr].w);
        }
    }

    #pragma unroll
    for (int rr = 0; rr < 4; ++rr) {
        int gr = row0 + rg * 4 + rr;
        if (gr >= N) continue;
        float nv = norm[gr];
        __half2 h0 = __floats2half2_rn(nv * acc[rr].x, nv * acc[rr].y);
        __half2 h1 = __floats2half2_rn(nv * acc[rr].z, nv * acc[rr].w);
        uint2 pk;
        pk.x = *reinterpret_cast<unsigned int*>(&h0);
        pk.y = *reinterpret_cast<unsigned int*>(&h1);
        xs[(size_t)gr * 16 + c4] = pk;
    }
}

// ================= fused GCN layer (fp16 xs, fp32 accumulate) =================
// wave per node; lane = (g = lane>>4 edge-slot 0..3, f = lane&15 uint2 idx).

__global__ __launch_bounds__(256) void layer_kernel(
        const int2* __restrict__ row_range, const int* __restrict__ col_sorted,
        const uint2* __restrict__ xin, const float* __restrict__ norm,
        void* __restrict__ xout_v, int N, int last) {
    int node = (blockIdx.x * blockDim.x + threadIdx.x) >> 6;
    int lane = threadIdx.x & 63;
    if (node >= N) return;
    const int f = lane & 15;      // features 4f .. 4f+3
    const int g = lane >> 4;      // edge slot 0..3

    int2 rr = row_range[node];
    int be = rr.x;
    int en = rr.y;
    float ax = 0.f, ay = 0.f, az = 0.f, aw = 0.f;

    for (int base = be; base < en; base += 64) {
        int m = en - base;
        if (m > 64) m = 64;
        int cv = (lane < m) ? col_sorted[base + lane] : 0;
        int t = 0;
        for (; t + 16 <= m; t += 16) {   // 16 edges: 4 loads, 4 shfl
            int c0 = __shfl(cv, t + 0 + g, 64);
            int c1 = __shfl(cv, t + 4 + g, 64);
            int c2 = __shfl(cv, t + 8 + g, 64);
            int c3 = __shfl(cv, t + 12 + g, 64);
            uint2 u0 = xin[(size_t)c0 * 16 + f];
            uint2 u1 = xin[(size_t)c1 * 16 + f];
            uint2 u2 = xin[(size_t)c2 * 16 + f];
            uint2 u3 = xin[(size_t)c3 * 16 + f];
            float2 p0 = __half22float2(*reinterpret_cast<__half2*>(&u0.x));
            float2 q0 = __half22float2(*reinterpret_cast<__half2*>(&u0.y));
            float2 p1 = __half22float2(*reinterpret_cast<__half2*>(&u1.x));
            float2 q1 = __half22float2(*reinterpret_cast<__half2*>(&u1.y));
            float2 p2 = __half22float2(*reinterpret_cast<__half2*>(&u2.x));
            float2 q2 = __half22float2(*reinterpret_cast<__half2*>(&u2.y));
            float2 p3 = __half22float2(*reinterpret_cast<__half2*>(&u3.x));
            float2 q3 = __half22float2(*reinterpret_cast<__half2*>(&u3.y));
            ax += (p0.x + p1.x) + (p2.x + p3.x);
            ay += (p0.y + p1.y) + (p2.y + p3.y);
            az += (q0.x + q1.x) + (q2.x + q3.x);
            aw += (q0.y + q1.y) + (q2.y + q3.y);
        }
        for (; t + 4 <= m; t += 4) {     // 4 edges: 1 load, 1 shfl
            int c = __shfl(cv, t + g, 64);
            uint2 u = xin[(size_t)c * 16 + f];
            float2 p = __half22float2(*reinterpret_cast<__half2*>(&u.x));
            float2 q = __half22float2(*reinterpret_cast<__half2*>(&u.y));
            ax += p.x; ay += p.y; az += q.x; aw += q.y;
        }
        int rem = m - t;
        if (rem > 0) {                   // tail: slots g < rem participate
            int c = __shfl(cv, t + g, 64);
            if (g < rem) {
                uint2 u = xin[(size_t)c * 16 + f];
                float2 p = __half22float2(*reinterpret_cast<__half2*>(&u.x));
                float2 q = __half22float2(*reinterpret_cast<__half2*>(&u.y));
                ax += p.x; ay += p.y; az += q.x; aw += q.y;
            }
        }
    }

    // reduce edge slots (lane bits 4,5)
    ax += __shfl_xor(ax, 16, 64); ax += __shfl_xor(ax, 32, 64);
    ay += __shfl_xor(ay, 16, 64); ay += __shfl_xor(ay, 32, 64);
    az += __shfl_xor(az, 16, 64); az += __shfl_xor(az, 32, 64);
    aw += __shfl_xor(aw, 16, 64); aw += __shfl_xor(aw, 32, 64);

    uint2 us = xin[(size_t)node * 16 + f];
    float2 sp = __half22float2(*reinterpret_cast<__half2*>(&us.x));
    float2 sq = __half22float2(*reinterpret_cast<__half2*>(&us.y));
    float nv = norm[node];
    float hx = nv * (ax + sp.x);
    float hy = nv * (ay + sp.y);
    float hz = nv * (az + sq.x);
    float hw = nv * (aw + sq.y);
    if (g == 0) {
        if (last) {
            reinterpret_cast<float4*>(xout_v)[(size_t)node * 16 + f] =
                make_float4(hx, hy, hz, hw);
        } else {
            __half2 o0 = __floats2half2_rn(nv * hx, nv * hy);
            __half2 o1 = __floats2half2_rn(nv * hz, nv * hw);
            uint2 pk;
            pk.x = *reinterpret_cast<unsigned int*>(&o0);
            pk.y = *reinterpret_cast<unsigned int*>(&o1);
            reinterpret_cast<uint2*>(xout_v)[(size_t)node * 16 + f] = pk;
        }
    }
}

extern "C" void kernel_launch(void* const* d_in, const int* in_sizes, int n_in,
                              void* d_out, int out_size, void* d_ws, size_t ws_size,
                              hipStream_t stream) {
    const float* x  = (const float*)d_in[0];
    const int*   ei = (const int*)d_in[1];
    const float* W  = (const float*)d_in[2];
    const float* b  = (const float*)d_in[3];
    float* out = (float*)d_out;

    const int N = in_sizes[0] / IN_DIM;
    const int E = in_sizes[1] / 2;
    const int* rows = ei;
    const int* cols = ei + E;
    const int NB = (N + 127) >> 7;

    char* wp = (char*)d_ws;
    auto alloc = [&](size_t bytes) {
        char* r = wp;
        wp += (bytes + 15) & ~(size_t)15;
        return r;
    };
    int*   pairs      = (int*)alloc((size_t)NB * BCAP * sizeof(int));
    int*   col_sorted = (int*)alloc((size_t)NB * BCAP * sizeof(int));
    int*   gcursor    = (int*)alloc(MAXNB * sizeof(int));
    int2*  row_range  = (int2*)alloc((size_t)N * sizeof(int2));
    float* norm       = (float*)alloc((size_t)N * sizeof(float));
    uint2* xsA        = (uint2*)alloc((size_t)N * 16 * sizeof(uint2));
    uint2* xsB        = (uint2*)alloc((size_t)N * 16 * sizeof(uint2));

    const int eblocks = (E + EPB - 1) / EPB;

    // ---- bucketed CSR build: zero -> fill -> sort (no global scan) ----
    zero_kernel<<<1, 512, 0, stream>>>(gcursor, MAXNB);
    bucket_fill_kernel<<<eblocks, 256, 0, stream>>>(rows, cols, gcursor, pairs, E, NB);
    bucket_sort_kernel<<<NB, 256, 0, stream>>>(pairs, gcursor, row_range, col_sorted, norm, N);

    // ---- xsA = fp16( norm * (x @ W + b) ) ----
    linear_kernel<<<(N + 63) / 64, 256, 0, stream>>>(x, W, b, norm, xsA, N);

    // ---- 3 layers: xsA -> xsB -> xsA -> out(f32) ----
    const int blocks = (N * 64 + 255) / 256;
    layer_kernel<<<blocks, 256, 0, stream>>>(row_range, col_sorted, xsA, norm, xsB, N, 0);
    layer_kernel<<<blocks, 256, 0, stream>>>(row_range, col_sorted, xsB, norm, xsA, N, 0);
    layer_kernel<<<blocks, 256, 0, stream>>>(row_range, col_sorted, xsA, norm, out, N, 1);
}